// Round 16
// baseline (261.237 us; speedup 1.0000x reference)
//
#include <hip/hip_runtime.h>
#include <math.h>

#define N_NODES 50000
#define IN_DIM 8
#define HID 32
#define D1 128   // HID * HEADS

// scan config: 256 thr × 4 elems = 1024 per block
#define SB 1024
#define NB ((N_NODES + SB - 1) / SB)   // 49

// dst-range partition: 8 groups (XCD-aligned via blockIdx&7 in fill/hist)
#define FG 8
#define FB 128
#define GRANGE (N_NODES / FG)          // 6250
#define STAGE_CAP 131072               // per-group capacity (mean 100k)

#define PART_BLOCKS 512
#define SD1_BLOCKS ((N_NODES + 255) / 256)    // 196

// ---------------------------------------------------------------------------
// FUSED partition + s1/d1 (NO histogram here — kept XCD-clean elsewhere).
// Partition: per-wave two-pass ballot ranking, zero LDS, zero barriers.
//   pass 1: count my-group sizes via __ballot/__popcll (lane l holds count
//           of group l); ONE global atomic per group per wave (16k total).
//   pass 2: re-read (L2-warm), rank = popc(mask & below), write (src,dst).
// sd1 blocks: s1[n]=x[n]·(W1 a_src), d1[n]=x[n]·(W1 a_dst).
// ---------------------------------------------------------------------------
__global__ void k_part_sd1(const int* __restrict__ src, const int* __restrict__ dst,
                           int* __restrict__ gpos, int2* __restrict__ stage,
                           const float* __restrict__ x, const float* __restrict__ W1,
                           const float* __restrict__ a1,
                           float* __restrict__ s1, float* __restrict__ d1,
                           int n_edges) {
    const int t = threadIdx.x;
    if (blockIdx.x < PART_BLOCKS) {
        const int lane = t & 63;
        const int wave = (blockIdx.x * 256 + t) >> 6;       // 0 .. NW-1
        const int NW = PART_BLOCKS * 4;
        const int nchunks = (n_edges + 63) / 64;
        // ---- pass 1: count ----
        int cnt_l = 0;                        // lane l (<8): #edges with group l
        for (int c = wave; c < nchunks; c += NW) {
            const int i = c * 64 + lane;
            int g = -1;
            if (i < n_edges) g = dst[i] / GRANGE;
#pragma unroll
            for (int q = 0; q < FG; ++q) {
                const unsigned long long m = __ballot(g == q);
                if (lane == q) cnt_l += __popcll(m);
            }
        }
        int run = 0;
        if (lane < FG) run = atomicAdd(&gpos[lane], cnt_l);
        // ---- pass 2: rank + write ----
        for (int c = wave; c < nchunks; c += NW) {
            const int i = c * 64 + lane;
            int g = -1, se = 0, de = 0;
            if (i < n_edges) { de = dst[i]; se = src[i]; g = de / GRANGE; }
            unsigned long long mymask = 0;
            int addq = 0;
#pragma unroll
            for (int q = 0; q < FG; ++q) {
                const unsigned long long m = __ballot(g == q);
                if (q == g) mymask = m;
                if (lane == q) addq = __popcll(m);
            }
            const int basev = __shfl(run, g & 7);
            if (g >= 0) {
                const int rank = __popcll(mymask & ((1ULL << lane) - 1));
                stage[g * STAGE_CAP + basev + rank] = make_int2(se, de);
            }
            run += addq;                      // lanes 0..7 advance their bases
        }
    } else {
        __shared__ float bs[IN_DIM], bd[IN_DIM];
        if (t < 16) {
            const int k = t & 7;
            const float* av = a1 + ((t < 8) ? 0 : D1);
            float acc = 0.f;
            for (int j = 0; j < D1; ++j) acc += W1[k * D1 + j] * av[j];
            if (t < 8) bs[k] = acc; else bd[k] = acc;
        }
        __syncthreads();
        const int node = (blockIdx.x - PART_BLOCKS) * blockDim.x + t;
        if (node >= N_NODES) return;
        const float4 x0 = *(const float4*)&x[node * 8];
        const float4 x1 = *(const float4*)&x[node * 8 + 4];
        s1[node] = x0.x*bs[0] + x0.y*bs[1] + x0.z*bs[2] + x0.w*bs[3]
                 + x1.x*bs[4] + x1.y*bs[5] + x1.z*bs[6] + x1.w*bs[7];
        d1[node] = x0.x*bd[0] + x0.y*bd[1] + x0.z*bd[2] + x0.w*bd[3]
                 + x1.x*bd[4] + x1.y*bd[5] + x1.z*bd[6] + x1.w*bd[7];
    }
}

// ---------------------------------------------------------------------------
// Histogram from staged records: group-g blocks read stage[g] coalesced and
// atomicAdd cnt strictly within g's dst range -> XCD-clean lines; also warms
// L2 for k_fill.
// ---------------------------------------------------------------------------
__global__ void k_hist_stage(const int2* __restrict__ stage,
                             const int* __restrict__ gpos,
                             int* __restrict__ cnt) {
    const int g = blockIdx.x & (FG - 1);
    const int blk = blockIdx.x >> 3;
    const int n = gpos[g];
    const int2* st = stage + (size_t)g * STAGE_CAP;
    for (int i = blk * blockDim.x + threadIdx.x; i < n; i += FB * blockDim.x)
        atomicAdd(&cnt[st[i].y], 1);
}

// ---------------------------------------------------------------------------
// Single-kernel scan: each of NB blocks redundantly computes all chunk sums
// (L2-resident), wave-0 scans them for the block's global offset, then the
// block scans its own chunk -> offs[]; cursor = offs.
// ---------------------------------------------------------------------------
__global__ void k_scan(const int* __restrict__ cnt, int* __restrict__ offs,
                       int* __restrict__ cursor) {
    const int t = threadIdx.x;
    const int lane = t & 63, wid = t >> 6;
    __shared__ int csum[64];
    __shared__ int s_boff;
    __shared__ int wtot[4];
    for (int j = wid; j < NB; j += 4) {
        const int cbase = j * SB + lane * 16;
        int ssum = 0;
#pragma unroll
        for (int q = 0; q < 4; ++q) {
            const int idx = cbase + q * 4;
            if (idx + 3 < N_NODES) {
                const int4 v = *(const int4*)&cnt[idx];
                ssum += v.x + v.y + v.z + v.w;
            }
        }
#pragma unroll
        for (int off = 32; off > 0; off >>= 1) ssum += __shfl_xor(ssum, off);
        if (lane == 0) csum[j] = ssum;
    }
    __syncthreads();
    if (t < 64) {
        int v = (t < NB) ? csum[t] : 0;
        int incl = v;
#pragma unroll
        for (int off = 1; off < 64; off <<= 1) {
            int u = __shfl_up(incl, off);
            if (t >= off) incl += u;
        }
        if (t == blockIdx.x) s_boff = incl - v;
        if (blockIdx.x == NB - 1 && t == NB - 1) offs[N_NODES] = incl;
    }
    const int base = blockIdx.x * SB + t * 4;
    int4 v = {0, 0, 0, 0};
    if (base + 3 < N_NODES) v = *(const int4*)&cnt[base];
    const int tsum = v.x + v.y + v.z + v.w;
    int incl = tsum;
#pragma unroll
    for (int off = 1; off < 64; off <<= 1) {
        int u = __shfl_up(incl, off);
        if (lane >= off) incl += u;
    }
    if (lane == 63) wtot[wid] = incl;
    __syncthreads();
    int woff = 0;
    for (int w = 0; w < wid; ++w) woff += wtot[w];
    const int excl = s_boff + woff + incl - tsum;
    if (base + 3 < N_NODES) {
        int4 o;
        o.x = excl;
        o.y = excl + v.x;
        o.z = excl + v.x + v.y;
        o.w = excl + v.x + v.y + v.z;
        *(int4*)&offs[base] = o;
        *(int4*)&cursor[base] = o;
    }
}

// ---------------------------------------------------------------------------
// Fill from staged per-group records (coalesced int2 reads; atomics and esrc
// writes are XCD-local since group g -> blockIdx&7 = g).
// ---------------------------------------------------------------------------
__global__ void k_fill(const int2* __restrict__ stage, const int* __restrict__ gpos,
                       int* __restrict__ cursor, int* __restrict__ esrc) {
    const int g = blockIdx.x & (FG - 1);
    const int blk = blockIdx.x >> 3;
    const int n = gpos[g];
    const int2* st = stage + (size_t)g * STAGE_CAP;
    for (int i = blk * blockDim.x + threadIdx.x; i < n; i += FB * blockDim.x) {
        const int2 e = st[i];
        esrc[atomicAdd(&cursor[e.y], 1)] = e.x;
    }
}

// ---------------------------------------------------------------------------
// Layer-1 aggregation in INPUT space (8-dim), single pass, 2 nodes/wave.
// 2 lanes/edge (float4 each) -> 16 edges in flight per half.
// ---------------------------------------------------------------------------
__global__ void k_aggr_x(const int* __restrict__ esrc, const int* __restrict__ offs,
                         const float* __restrict__ s, const float* __restrict__ d,
                         const float* __restrict__ x, float* __restrict__ xa) {
    const int w = (blockIdx.x * blockDim.x + threadIdx.x) >> 6;
    const int lane = threadIdx.x & 63;
    const int half = lane >> 5, sub = lane & 31;
    const int node = w * 2 + half;
    if (node >= N_NODES) return;
    const int start = offs[node], end = offs[node + 1];
    const int deg = end - start;
    const float dn = d[node];
    const int slot = sub >> 1;       // 16 edge slots per half
    const int cp = sub & 1;          // float4 -> cols 4cp..4cp+3
    float4 acc = {0.f, 0.f, 0.f, 0.f};
    float wsum = 0.f;
    for (int idx = slot; idx < deg; idx += 16) {
        const int se = esrc[start + idx];
        float a = s[se] + dn;
        a = a > 0.f ? a : 0.2f * a;
        const float ww = expf(a);
        const float4 v = *(const float4*)&x[se * IN_DIM + cp * 4];
        acc.x += ww * v.x;  acc.y += ww * v.y;
        acc.z += ww * v.z;  acc.w += ww * v.w;
        wsum += ww;
    }
#pragma unroll
    for (int off = 2; off < 32; off <<= 1) {
        acc.x += __shfl_xor(acc.x, off);
        acc.y += __shfl_xor(acc.y, off);
        acc.z += __shfl_xor(acc.z, off);
        acc.w += __shfl_xor(acc.w, off);
        wsum  += __shfl_xor(wsum, off);
    }
    const float inv = 1.f / (wsum + 1e-9f);
    acc.x *= inv;  acc.y *= inv;  acc.z *= inv;  acc.w *= inv;
    if (sub < 2) *(float4*)&xa[node * IN_DIM + sub * 4] = acc;
}

// ---------------------------------------------------------------------------
// Fused node mid, 4 THREADS PER NODE (column split).
// ---------------------------------------------------------------------------
__global__ void k_node_mid(const float* __restrict__ xa,
                           const float* __restrict__ W1,
                           const float* __restrict__ W2,
                           const float* __restrict__ a2,
                           float* __restrict__ Wh2,
                           float* __restrict__ s2, float* __restrict__ d2) {
    const int tid = blockIdx.x * blockDim.x + threadIdx.x;
    const int node = tid >> 2;
    const int q = tid & 3;
    if (node >= N_NODES) return;
    const float4 x0 = *(const float4*)&xa[node * 8];
    const float4 x1 = *(const float4*)&xa[node * 8 + 4];
    float acc[8];
#pragma unroll
    for (int j = 0; j < 8; ++j) acc[j] = 0.f;
    const float* W2q = W2 + q * 8;
#pragma unroll 4
    for (int k = 0; k < D1; ++k) {
        float h = x0.x * W1[0 * D1 + k] + x0.y * W1[1 * D1 + k]
                + x0.z * W1[2 * D1 + k] + x0.w * W1[3 * D1 + k]
                + x1.x * W1[4 * D1 + k] + x1.y * W1[5 * D1 + k]
                + x1.z * W1[6 * D1 + k] + x1.w * W1[7 * D1 + k];
        h = h > 0.f ? h : (expf(h) - 1.f);       // elu
        const float4 w0 = *(const float4*)&W2q[k * HID];
        const float4 w1 = *(const float4*)&W2q[k * HID + 4];
        acc[0] += h * w0.x;  acc[1] += h * w0.y;
        acc[2] += h * w0.z;  acc[3] += h * w0.w;
        acc[4] += h * w1.x;  acc[5] += h * w1.y;
        acc[6] += h * w1.z;  acc[7] += h * w1.w;
    }
    float ss = 0.f, dd = 0.f;
#pragma unroll
    for (int j = 0; j < 8; ++j) {
        ss += acc[j] * a2[q * 8 + j];
        dd += acc[j] * a2[HID + q * 8 + j];
    }
    ss += __shfl_xor(ss, 1);  ss += __shfl_xor(ss, 2);
    dd += __shfl_xor(dd, 1);  dd += __shfl_xor(dd, 2);
    if (q == 0) { s2[node] = ss; d2[node] = dd; }
    float4* o = (float4*)&Wh2[node * HID + q * 8];
    o[0] = make_float4(acc[0], acc[1], acc[2], acc[3]);
    o[1] = make_float4(acc[4], acc[5], acc[6], acc[7]);
}

// ---------------------------------------------------------------------------
// Layer-2 aggregation + FUSED MLP HEAD, single pass, 2 nodes/wave.
// 8 lanes/edge (float4 each) -> 4 edges in flight per half.
// ---------------------------------------------------------------------------
__global__ void k_aggr32_head(const int* __restrict__ esrc, const int* __restrict__ offs,
                              const float* __restrict__ s, const float* __restrict__ d,
                              const float* __restrict__ Wh,
                              const float* __restrict__ hw1, const float* __restrict__ hb1,
                              const float* __restrict__ hw2, const float* __restrict__ hb2,
                              float* __restrict__ scores) {
    const int w = (blockIdx.x * blockDim.x + threadIdx.x) >> 6;
    const int lane = threadIdx.x & 63;
    const int half = lane >> 5, sub = lane & 31, base = lane & 32;
    const int node = w * 2 + half;
    if (node >= N_NODES) return;
    const int start = offs[node], end = offs[node + 1];
    const int deg = end - start;
    const float dn = d[node];
    const int slot = sub >> 3;       // 4 edge slots per half
    const int cp = sub & 7;          // float4 -> cols 4cp..4cp+3
    float4 acc = {0.f, 0.f, 0.f, 0.f};
    float wsum = 0.f;
    for (int idx = slot; idx < deg; idx += 4) {
        const int se = esrc[start + idx];
        float a = s[se] + dn;
        a = a > 0.f ? a : 0.2f * a;
        const float ww = expf(a);
        const float4 v = *(const float4*)&Wh[se * HID + cp * 4];
        acc.x += ww * v.x;  acc.y += ww * v.y;
        acc.z += ww * v.z;  acc.w += ww * v.w;
        wsum += ww;
    }
#pragma unroll
    for (int off = 8; off < 32; off <<= 1) {
        acc.x += __shfl_xor(acc.x, off);
        acc.y += __shfl_xor(acc.y, off);
        acc.z += __shfl_xor(acc.z, off);
        acc.w += __shfl_xor(acc.w, off);
        wsum  += __shfl_xor(wsum, off);
    }
    const float inv = 1.f / (wsum + 1e-9f);
    acc.x *= inv;  acc.y *= inv;  acc.z *= inv;  acc.w *= inv;
    // ---- fused head (per half; lane sub = output col c) ----
    const int srcl = base + (sub >> 2);
    const float g0 = __shfl(acc.x, srcl);
    const float g1 = __shfl(acc.y, srcl);
    const float g2 = __shfl(acc.z, srcl);
    const float g3 = __shfl(acc.w, srcl);
    const int r = sub & 3;
    float v = (r == 0) ? g0 : (r == 1) ? g1 : (r == 2) ? g2 : g3;
    const float h = v > 0.f ? v : (expf(v) - 1.f);   // elu
    float z = hb1[sub];
#pragma unroll
    for (int k = 0; k < HID; ++k) {
        const float hk = __shfl(h, base + k);
        z += hk * hw1[k * HID + sub];
    }
    z = 0.5f * z * (1.f + erff(z * 0.7071067811865475f));  // exact gelu
    float sc = z * hw2[sub];
#pragma unroll
    for (int off = 16; off > 0; off >>= 1) sc += __shfl_xor(sc, off);
    if (sub == 0) scores[node] = sc + hb2[0];
}

// ---------------------------------------------------------------------------
extern "C" void kernel_launch(void* const* d_in, const int* in_sizes, int n_in,
                              void* d_out, int out_size, void* d_ws, size_t ws_size,
                              hipStream_t stream) {
    const float* x   = (const float*)d_in[0];
    const int*   ei  = (const int*)d_in[1];
    const float* W1  = (const float*)d_in[2];
    const float* a1  = (const float*)d_in[3];
    const float* W2  = (const float*)d_in[4];
    const float* a2  = (const float*)d_in[5];
    const float* hw1 = (const float*)d_in[6];
    const float* hb1 = (const float*)d_in[7];
    const float* hw2 = (const float*)d_in[8];
    const float* hb2 = (const float*)d_in[9];
    float* out = (float*)d_out;

    const int n_edges = in_sizes[1] / 2;
    const int* src = ei;
    const int* dst = ei + n_edges;

    // workspace carve-up
    float* p = (float*)d_ws;
    float* xa   = p; p += (size_t)N_NODES * IN_DIM;
    float* Wh2  = p; p += (size_t)N_NODES * HID;
    float* s1   = p; p += N_NODES;
    float* d1   = p; p += N_NODES;
    float* s2   = p; p += N_NODES;
    float* d2   = p; p += N_NODES;
    int* cnt    = (int*)p; p += N_NODES;        // histogram counts
    int* gpos   = (int*)p; p += FG;             // per-group staged counts
    int* cursor = (int*)p; p += N_NODES;        // fill cursors (init by scan)
    int* offs   = (int*)p; p += N_NODES + 1;    // CSR offsets
    int* esrc   = (int*)p; p += n_edges;        // src ids sorted by dst
    int2* stage = (int2*)p;                     // 8 × STAGE_CAP int2 (8.4 MB)

    // zero cnt + gpos in one memset (contiguous)
    hipMemsetAsync(cnt, 0, (N_NODES + FG) * sizeof(int), stream);

    const int AGGR_BLOCKS = (N_NODES * 32 + 255) / 256;   // 2 nodes per wave

    // edge partition (one read) + s1/d1; then XCD-clean histogram from stage
    k_part_sd1<<<PART_BLOCKS + SD1_BLOCKS, 256, 0, stream>>>(
        src, dst, gpos, stage, x, W1, a1, s1, d1, n_edges);
    k_hist_stage<<<FG * FB, 256, 0, stream>>>(stage, gpos, cnt);
    k_scan<<<NB, 256, 0, stream>>>(cnt, offs, cursor);
    k_fill<<<FG * FB, 256, 0, stream>>>(stage, gpos, cursor, esrc);

    // ----- layer 1 (aggregated in 8-dim input space; Wh1 never built) -----
    k_aggr_x<<<AGGR_BLOCKS, 256, 0, stream>>>(esrc, offs, s1, d1, x, xa);

    // ----- layer 2 (4-thread-per-node mid; aggregation fused with head) -----
    k_node_mid<<<(N_NODES * 4 + 255) / 256, 256, 0, stream>>>(xa, W1, W2, a2, Wh2, s2, d2);
    k_aggr32_head<<<AGGR_BLOCKS, 256, 0, stream>>>(esrc, offs, s2, d2, Wh2,
                                                   hw1, hb1, hw2, hb2, out);
}

// Round 17
// 237.463 us; speedup vs baseline: 1.1001x; 1.1001x over previous
//
#include <hip/hip_runtime.h>
#include <math.h>

#define N_NODES 50000
#define IN_DIM 8
#define HID 32
#define D1 128   // HID * HEADS

// scan config: 256 thr × 4 elems = 1024 per block
#define SB 1024
#define NB ((N_NODES + SB - 1) / SB)   // 49

// XCD-partitioned CSR build: 8 groups (g = blockIdx&7 -> same XCD under
// round-robin dispatch), each group owns dst range of N_NODES/8 = 6250.
#define FG 8
#define FB 128          // blocks per group
#define GRANGE (N_NODES / FG)
#define HIST_BLOCKS (FG * FB)                 // 1024
#define SD1_BLOCKS ((N_NODES + 255) / 256)    // 196

// ---------------------------------------------------------------------------
// FUSED: histogram (blocks 0..1023) + s1/d1 fold (blocks 1024..1219).
// Independent outputs; block-range split saves one dispatch gap.
// ---------------------------------------------------------------------------
__global__ void k_hist_sd1(const int* __restrict__ dst, int* __restrict__ cnt,
                           const float* __restrict__ x, const float* __restrict__ W1,
                           const float* __restrict__ a1,
                           float* __restrict__ s1, float* __restrict__ d1,
                           int n_edges) {
    __shared__ float bs[IN_DIM], bd[IN_DIM];
    const int t = threadIdx.x;
    if (blockIdx.x < HIST_BLOCKS) {
        // ---- histogram ----
        const int g = blockIdx.x & (FG - 1);
        const int blk = blockIdx.x >> 3;
        const int lo = g * GRANGE, hi = lo + GRANGE;
        const int base = blk * blockDim.x + t;
        const int step = FB * blockDim.x;
        for (int i = base; i * 4 < n_edges; i += step) {
            const int4 d4 = *(const int4*)&dst[i * 4];
            if (d4.x >= lo && d4.x < hi) atomicAdd(&cnt[d4.x], 1);
            if (d4.y >= lo && d4.y < hi) atomicAdd(&cnt[d4.y], 1);
            if (d4.z >= lo && d4.z < hi) atomicAdd(&cnt[d4.z], 1);
            if (d4.w >= lo && d4.w < hi) atomicAdd(&cnt[d4.w], 1);
        }
    } else {
        // ---- s1/d1: s1[n] = x[n]·(W1 a_src), d1[n] = x[n]·(W1 a_dst) ----
        if (t < 16) {
            const int k = t & 7;
            const float* av = a1 + ((t < 8) ? 0 : D1);
            float acc = 0.f;
            for (int j = 0; j < D1; ++j) acc += W1[k * D1 + j] * av[j];
            if (t < 8) bs[k] = acc; else bd[k] = acc;
        }
        __syncthreads();
        const int node = (blockIdx.x - HIST_BLOCKS) * blockDim.x + t;
        if (node >= N_NODES) return;
        const float4 x0 = *(const float4*)&x[node * 8];
        const float4 x1 = *(const float4*)&x[node * 8 + 4];
        s1[node] = x0.x*bs[0] + x0.y*bs[1] + x0.z*bs[2] + x0.w*bs[3]
                 + x1.x*bs[4] + x1.y*bs[5] + x1.z*bs[6] + x1.w*bs[7];
        d1[node] = x0.x*bd[0] + x0.y*bd[1] + x0.z*bd[2] + x0.w*bd[3]
                 + x1.x*bd[4] + x1.y*bd[5] + x1.z*bd[6] + x1.w*bd[7];
    }
}

// ---------------------------------------------------------------------------
// FUSED single-kernel scan: each of the NB blocks redundantly computes ALL
// chunk sums (200 KB L2-resident), wave-0 scans them for this block's global
// offset, then the block scans its own chunk -> offs[]; cursor = offs.
// ---------------------------------------------------------------------------
__global__ void k_scan(const int* __restrict__ cnt, int* __restrict__ offs,
                       int* __restrict__ cursor) {
    const int t = threadIdx.x;
    const int lane = t & 63, wid = t >> 6;
    __shared__ int csum[64];
    __shared__ int s_boff;
    __shared__ int wtot[4];
    // step 1: all chunk sums (4 waves cover NB chunks round-robin)
    for (int j = wid; j < NB; j += 4) {
        const int cbase = j * SB + lane * 16;
        int ssum = 0;
#pragma unroll
        for (int q = 0; q < 4; ++q) {
            const int idx = cbase + q * 4;
            if (idx + 3 < N_NODES) {
                const int4 v = *(const int4*)&cnt[idx];
                ssum += v.x + v.y + v.z + v.w;
            }
        }
#pragma unroll
        for (int off = 32; off > 0; off >>= 1) ssum += __shfl_xor(ssum, off);
        if (lane == 0) csum[j] = ssum;
    }
    __syncthreads();
    // step 2: wave 0 scans chunk sums
    if (t < 64) {
        int v = (t < NB) ? csum[t] : 0;
        int incl = v;
#pragma unroll
        for (int off = 1; off < 64; off <<= 1) {
            int u = __shfl_up(incl, off);
            if (t >= off) incl += u;
        }
        if (t == blockIdx.x) s_boff = incl - v;
        if (blockIdx.x == NB - 1 && t == NB - 1) offs[N_NODES] = incl;
    }
    // step 3: own chunk exclusive scan
    const int base = blockIdx.x * SB + t * 4;
    int4 v = {0, 0, 0, 0};
    if (base + 3 < N_NODES) v = *(const int4*)&cnt[base];
    const int tsum = v.x + v.y + v.z + v.w;
    int incl = tsum;
#pragma unroll
    for (int off = 1; off < 64; off <<= 1) {
        int u = __shfl_up(incl, off);
        if (lane >= off) incl += u;
    }
    if (lane == 63) wtot[wid] = incl;
    __syncthreads();                      // guards wtot AND s_boff
    int woff = 0;
    for (int w = 0; w < wid; ++w) woff += wtot[w];
    const int excl = s_boff + woff + incl - tsum;
    if (base + 3 < N_NODES) {
        int4 o;
        o.x = excl;
        o.y = excl + v.x;
        o.z = excl + v.x + v.y;
        o.w = excl + v.x + v.y + v.z;
        *(int4*)&offs[base] = o;
        *(int4*)&cursor[base] = o;
    }
}

// ---------------------------------------------------------------------------
// Fill: src int4 loaded only when some dst of the 4 is in range (~41%).
// ---------------------------------------------------------------------------
__global__ void k_fill(const int* __restrict__ src, const int* __restrict__ dst,
                       int* __restrict__ cursor,
                       int* __restrict__ esrc, int n_edges) {
    const int g = blockIdx.x & (FG - 1);
    const int blk = blockIdx.x >> 3;
    const int lo = g * GRANGE, hi = lo + GRANGE;
    const int base = blk * blockDim.x + threadIdx.x;
    const int step = FB * blockDim.x;
    for (int i = base; i * 4 < n_edges; i += step) {
        const int4 d4 = *(const int4*)&dst[i * 4];
        const bool mx = d4.x >= lo && d4.x < hi;
        const bool my = d4.y >= lo && d4.y < hi;
        const bool mz = d4.z >= lo && d4.z < hi;
        const bool mw = d4.w >= lo && d4.w < hi;
        if (mx | my | mz | mw) {
            const int4 s4 = *(const int4*)&src[i * 4];
            if (mx) esrc[atomicAdd(&cursor[d4.x], 1)] = s4.x;
            if (my) esrc[atomicAdd(&cursor[d4.y], 1)] = s4.y;
            if (mz) esrc[atomicAdd(&cursor[d4.z], 1)] = s4.z;
            if (mw) esrc[atomicAdd(&cursor[d4.w], 1)] = s4.w;
        }
    }
}

// ---------------------------------------------------------------------------
// Layer-1 aggregation in INPUT space (8-dim), single pass, 2 nodes/wave.
// 2 lanes/edge (float4 each) -> 16 edges in flight per half.
// ---------------------------------------------------------------------------
__global__ void k_aggr_x(const int* __restrict__ esrc, const int* __restrict__ offs,
                         const float* __restrict__ s, const float* __restrict__ d,
                         const float* __restrict__ x, float* __restrict__ xa) {
    const int w = (blockIdx.x * blockDim.x + threadIdx.x) >> 6;
    const int lane = threadIdx.x & 63;
    const int half = lane >> 5, sub = lane & 31;
    const int node = w * 2 + half;
    if (node >= N_NODES) return;
    const int start = offs[node], end = offs[node + 1];
    const int deg = end - start;
    const float dn = d[node];
    const int slot = sub >> 1;       // 16 edge slots per half
    const int cp = sub & 1;          // float4 -> cols 4cp..4cp+3
    float4 acc = {0.f, 0.f, 0.f, 0.f};
    float wsum = 0.f;
    for (int idx = slot; idx < deg; idx += 16) {
        const int se = esrc[start + idx];
        float a = s[se] + dn;
        a = a > 0.f ? a : 0.2f * a;
        const float ww = expf(a);
        const float4 v = *(const float4*)&x[se * IN_DIM + cp * 4];
        acc.x += ww * v.x;  acc.y += ww * v.y;
        acc.z += ww * v.z;  acc.w += ww * v.w;
        wsum += ww;
    }
#pragma unroll
    for (int off = 2; off < 32; off <<= 1) {
        acc.x += __shfl_xor(acc.x, off);
        acc.y += __shfl_xor(acc.y, off);
        acc.z += __shfl_xor(acc.z, off);
        acc.w += __shfl_xor(acc.w, off);
        wsum  += __shfl_xor(wsum, off);
    }
    const float inv = 1.f / (wsum + 1e-9f);
    acc.x *= inv;  acc.y *= inv;  acc.z *= inv;  acc.w *= inv;
    if (sub < 2) *(float4*)&xa[node * IN_DIM + sub * 4] = acc;
}

// ---------------------------------------------------------------------------
// Fused node mid, 4 THREADS PER NODE (column split).
// ---------------------------------------------------------------------------
__global__ void k_node_mid(const float* __restrict__ xa,
                           const float* __restrict__ W1,
                           const float* __restrict__ W2,
                           const float* __restrict__ a2,
                           float* __restrict__ Wh2,
                           float* __restrict__ s2, float* __restrict__ d2) {
    const int tid = blockIdx.x * blockDim.x + threadIdx.x;
    const int node = tid >> 2;
    const int q = tid & 3;
    if (node >= N_NODES) return;
    const float4 x0 = *(const float4*)&xa[node * 8];
    const float4 x1 = *(const float4*)&xa[node * 8 + 4];
    float acc[8];
#pragma unroll
    for (int j = 0; j < 8; ++j) acc[j] = 0.f;
    const float* W2q = W2 + q * 8;
#pragma unroll 4
    for (int k = 0; k < D1; ++k) {
        float h = x0.x * W1[0 * D1 + k] + x0.y * W1[1 * D1 + k]
                + x0.z * W1[2 * D1 + k] + x0.w * W1[3 * D1 + k]
                + x1.x * W1[4 * D1 + k] + x1.y * W1[5 * D1 + k]
                + x1.z * W1[6 * D1 + k] + x1.w * W1[7 * D1 + k];
        h = h > 0.f ? h : (expf(h) - 1.f);       // elu
        const float4 w0 = *(const float4*)&W2q[k * HID];
        const float4 w1 = *(const float4*)&W2q[k * HID + 4];
        acc[0] += h * w0.x;  acc[1] += h * w0.y;
        acc[2] += h * w0.z;  acc[3] += h * w0.w;
        acc[4] += h * w1.x;  acc[5] += h * w1.y;
        acc[6] += h * w1.z;  acc[7] += h * w1.w;
    }
    float ss = 0.f, dd = 0.f;
#pragma unroll
    for (int j = 0; j < 8; ++j) {
        ss += acc[j] * a2[q * 8 + j];
        dd += acc[j] * a2[HID + q * 8 + j];
    }
    ss += __shfl_xor(ss, 1);  ss += __shfl_xor(ss, 2);
    dd += __shfl_xor(dd, 1);  dd += __shfl_xor(dd, 2);
    if (q == 0) { s2[node] = ss; d2[node] = dd; }
    float4* o = (float4*)&Wh2[node * HID + q * 8];
    o[0] = make_float4(acc[0], acc[1], acc[2], acc[3]);
    o[1] = make_float4(acc[4], acc[5], acc[6], acc[7]);
}

// ---------------------------------------------------------------------------
// Layer-2 aggregation + FUSED MLP HEAD, single pass, 2 nodes/wave.
// 8 lanes/edge (float4 each) -> 4 edges in flight per half.
// ---------------------------------------------------------------------------
__global__ void k_aggr32_head(const int* __restrict__ esrc, const int* __restrict__ offs,
                              const float* __restrict__ s, const float* __restrict__ d,
                              const float* __restrict__ Wh,
                              const float* __restrict__ hw1, const float* __restrict__ hb1,
                              const float* __restrict__ hw2, const float* __restrict__ hb2,
                              float* __restrict__ scores) {
    const int w = (blockIdx.x * blockDim.x + threadIdx.x) >> 6;
    const int lane = threadIdx.x & 63;
    const int half = lane >> 5, sub = lane & 31, base = lane & 32;
    const int node = w * 2 + half;
    if (node >= N_NODES) return;
    const int start = offs[node], end = offs[node + 1];
    const int deg = end - start;
    const float dn = d[node];
    const int slot = sub >> 3;       // 4 edge slots per half
    const int cp = sub & 7;          // float4 -> cols 4cp..4cp+3
    float4 acc = {0.f, 0.f, 0.f, 0.f};
    float wsum = 0.f;
    for (int idx = slot; idx < deg; idx += 4) {
        const int se = esrc[start + idx];
        float a = s[se] + dn;
        a = a > 0.f ? a : 0.2f * a;
        const float ww = expf(a);
        const float4 v = *(const float4*)&Wh[se * HID + cp * 4];
        acc.x += ww * v.x;  acc.y += ww * v.y;
        acc.z += ww * v.z;  acc.w += ww * v.w;
        wsum += ww;
    }
#pragma unroll
    for (int off = 8; off < 32; off <<= 1) {
        acc.x += __shfl_xor(acc.x, off);
        acc.y += __shfl_xor(acc.y, off);
        acc.z += __shfl_xor(acc.z, off);
        acc.w += __shfl_xor(acc.w, off);
        wsum  += __shfl_xor(wsum, off);
    }
    const float inv = 1.f / (wsum + 1e-9f);
    acc.x *= inv;  acc.y *= inv;  acc.z *= inv;  acc.w *= inv;
    // ---- fused head (per half; lane sub = output col c) ----
    const int srcl = base + (sub >> 2);
    const float g0 = __shfl(acc.x, srcl);
    const float g1 = __shfl(acc.y, srcl);
    const float g2 = __shfl(acc.z, srcl);
    const float g3 = __shfl(acc.w, srcl);
    const int r = sub & 3;
    float v = (r == 0) ? g0 : (r == 1) ? g1 : (r == 2) ? g2 : g3;
    const float h = v > 0.f ? v : (expf(v) - 1.f);   // elu
    float z = hb1[sub];
#pragma unroll
    for (int k = 0; k < HID; ++k) {
        const float hk = __shfl(h, base + k);
        z += hk * hw1[k * HID + sub];
    }
    z = 0.5f * z * (1.f + erff(z * 0.7071067811865475f));  // exact gelu
    float sc = z * hw2[sub];
#pragma unroll
    for (int off = 16; off > 0; off >>= 1) sc += __shfl_xor(sc, off);
    if (sub == 0) scores[node] = sc + hb2[0];
}

// ---------------------------------------------------------------------------
extern "C" void kernel_launch(void* const* d_in, const int* in_sizes, int n_in,
                              void* d_out, int out_size, void* d_ws, size_t ws_size,
                              hipStream_t stream) {
    const float* x   = (const float*)d_in[0];
    const int*   ei  = (const int*)d_in[1];
    const float* W1  = (const float*)d_in[2];
    const float* a1  = (const float*)d_in[3];
    const float* W2  = (const float*)d_in[4];
    const float* a2  = (const float*)d_in[5];
    const float* hw1 = (const float*)d_in[6];
    const float* hb1 = (const float*)d_in[7];
    const float* hw2 = (const float*)d_in[8];
    const float* hb2 = (const float*)d_in[9];
    float* out = (float*)d_out;

    const int n_edges = in_sizes[1] / 2;
    const int* src = ei;
    const int* dst = ei + n_edges;

    // workspace carve-up
    float* p = (float*)d_ws;
    float* xa   = p; p += (size_t)N_NODES * IN_DIM;
    float* Wh2  = p; p += (size_t)N_NODES * HID;
    float* s1   = p; p += N_NODES;
    float* d1   = p; p += N_NODES;
    float* s2   = p; p += N_NODES;
    float* d2   = p; p += N_NODES;
    int* cnt    = (int*)p; p += N_NODES;        // histogram counts
    int* cursor = (int*)p; p += N_NODES;        // fill cursors (init by scan)
    int* offs   = (int*)p; p += N_NODES + 1;    // CSR offsets
    int* esrc   = (int*)p; p += n_edges;        // src ids sorted by dst

    hipMemsetAsync(cnt, 0, N_NODES * sizeof(int), stream);

    const int AGGR_BLOCKS = (N_NODES * 32 + 255) / 256;   // 2 nodes per wave

    // CSR build + s1/d1 (fused), single-kernel scan, fill
    k_hist_sd1<<<HIST_BLOCKS + SD1_BLOCKS, 256, 0, stream>>>(
        dst, cnt, x, W1, a1, s1, d1, n_edges);
    k_scan<<<NB, 256, 0, stream>>>(cnt, offs, cursor);
    k_fill<<<FG * FB, 256, 0, stream>>>(src, dst, cursor, esrc, n_edges);

    // ----- layer 1 (aggregated in 8-dim input space; Wh1 never built) -----
    k_aggr_x<<<AGGR_BLOCKS, 256, 0, stream>>>(esrc, offs, s1, d1, x, xa);

    // ----- layer 2 (4-thread-per-node mid; aggregation fused with head) -----
    k_node_mid<<<(N_NODES * 4 + 255) / 256, 256, 0, stream>>>(xa, W1, W2, a2, Wh2, s2, d2);
    k_aggr32_head<<<AGGR_BLOCKS, 256, 0, stream>>>(esrc, offs, s2, d2, Wh2,
                                                   hw1, hb1, hw2, hb2, out);
}